// Round 17
// baseline (1191.424 us; speedup 1.0000x reference)
//
#include <hip/hip_runtime.h>
#include <cstdint>
#include <cstddef>

typedef unsigned short u16;
typedef __attribute__((ext_vector_type(8))) __bf16 bf16x8;
typedef __attribute__((ext_vector_type(4))) float f32x4;

__device__ __forceinline__ f32x4 mfma_16x16x32(bf16x8 a, bf16x8 b, f32x4 c) {
  return __builtin_amdgcn_mfma_f32_16x16x32_bf16(a, b, c, 0, 0, 0);
}

__device__ __forceinline__ u16 f2bf(float f) {
  union { float f; uint32_t u; } c; c.f = f;
  uint32_t u = c.u + 0x7FFFu + ((c.u >> 16) & 1u);
  return (u16)(u >> 16);
}

__device__ __forceinline__ float bf2f(u16 x) {
  union { uint32_t u; float f; } c; c.u = ((uint32_t)x) << 16;
  return c.f;
}

__device__ __forceinline__ void gload_lds16(const void* g, void* l) {
  __builtin_amdgcn_global_load_lds(
      (__attribute__((address_space(1))) void*)(uintptr_t)g,
      (__attribute__((address_space(3))) void*)l, 16, 0, 0);
}

// ===========================================================================
// Ring GEMM. MR=8: BM=256, 4-slot ring, dist 3 (128 KB).  MR=4: BM=128,
// NEW 5-slot ring, dist 4 (120 KB, occupancy unchanged at 1 block/CU) —
// one extra K-step of load-latency cover; steady vmcnt(9), never 0.
// Hazards: STAGE(s+DIST) targets slot read at step s-1 (drained by its
// lgkmcnt(0)+barrier); RAW via counted vmcnt(3*ahead). One barrier/K-step.
// Swizzle sigma(r)=(r>>1)&3 on 16B granules on BOTH sides (conflict-free).
// ===========================================================================
template<int MR, bool OUT_BF16, bool RELU, bool ACC>
__global__ __launch_bounds__(512, 2) void gemm_ring(
    const u16* __restrict__ A, int lda, const u16* __restrict__ Bt, int ldb,
    const float* __restrict__ bias, void* Cout, int ldc,
    int M, int N, int K)
{
  constexpr int BM = MR * 32;
  constexpr int SLOT = (BM + 256) * 32;
  constexpr int NS   = (MR == 8) ? 4 : 5;    // ring slots
  constexpr int DIST = (MR == 8) ? 3 : 4;    // prefetch distance
  __shared__ u16 ring[NS * SLOT];

  const int tid = threadIdx.x;
  const int lane = tid & 63, wave = tid >> 6;
  const int wm = wave >> 2, wn = wave & 3;
  const int m0 = blockIdx.x * BM, n0 = blockIdx.y * 256;

  const int cA0 = tid, rA0 = cA0 >> 2;
  const u16* gA0 = A + (size_t)(m0 + rA0) * lda + (((cA0 & 3) ^ ((rA0 >> 1) & 3)) * 8);
  const int cA1 = tid + 512, rA1 = cA1 >> 2;
  const u16* gA1 = A + (size_t)(m0 + (MR == 8 ? rA1 : 0)) * lda + (((cA1 & 3) ^ ((rA1 >> 1) & 3)) * 8);
  const int cB0 = tid, rB0 = cB0 >> 2;
  const int cB1 = tid + 512, rB1 = cB1 >> 2;
  const u16* gB0 = Bt + (size_t)(n0 + rB0) * ldb + (((cB0 & 3) ^ ((rB0 >> 1) & 3)) * 8);
  const u16* gB1 = Bt + (size_t)(n0 + rB1) * ldb + (((cB1 & 3) ^ ((rB1 >> 1) & 3)) * 8);

  const int NK = K >> 5;

  auto STAGE = [&](int s, int ph) {
    u16* Sb = &ring[ph * SLOT];
    const int ko = s * 32;
    gload_lds16(gA0 + ko, Sb + cA0 * 8);
    if constexpr (MR == 8) gload_lds16(gA1 + ko, Sb + cA1 * 8);
    gload_lds16(gB0 + ko, Sb + BM * 32 + cB0 * 8);
    gload_lds16(gB1 + ko, Sb + BM * 32 + cB1 * 8);
  };
  auto WAITV = [&](int ahead) {
    if constexpr (MR == 8) {
      if (ahead >= 2)      asm volatile("s_waitcnt vmcnt(8)" ::: "memory");
      else if (ahead == 1) asm volatile("s_waitcnt vmcnt(4)" ::: "memory");
      else                 asm volatile("s_waitcnt vmcnt(0)" ::: "memory");
    } else {
      if (ahead >= 3)      asm volatile("s_waitcnt vmcnt(9)" ::: "memory");
      else if (ahead == 2) asm volatile("s_waitcnt vmcnt(6)" ::: "memory");
      else if (ahead == 1) asm volatile("s_waitcnt vmcnt(3)" ::: "memory");
      else                 asm volatile("s_waitcnt vmcnt(0)" ::: "memory");
    }
  };

  const int fr = lane & 15, g = lane >> 4;
  const int foff = fr * 32 + ((g ^ ((fr >> 1) & 3)) * 8);

  f32x4 acc[MR][4];
  #pragma unroll
  for (int m = 0; m < MR; m++)
    #pragma unroll
    for (int n = 0; n < 4; n++) acc[m][n] = f32x4{0.f, 0.f, 0.f, 0.f};

  for (int i = 0; i < DIST && i < NK; ++i) STAGE(i, i);
  {
    int a0 = (NK - 1 < DIST - 1) ? NK - 1 : DIST - 1;
    WAITV(a0);
  }
  __builtin_amdgcn_s_barrier();
  __builtin_amdgcn_sched_barrier(0);

  int rp = 0;                                // physical slot of step s
  for (int s = 0; s < NK; ++s) {
    const u16* As = &ring[rp * SLOT];
    const u16* Bs = As + BM * 32;

    bf16x8 bf[4];
    #pragma unroll
    for (int n = 0; n < 4; n++)
      bf[n] = *(const bf16x8*)(Bs + (wn * 64 + n * 16) * 32 + foff);
    bf16x8 af[4];
    #pragma unroll
    for (int m = 0; m < 4; m++)
      af[m] = *(const bf16x8*)(As + (wm * (MR * 16) + m * 16) * 32 + foff);

    if (s + DIST < NK) {
      int sp = rp + DIST; if (sp >= NS) sp -= NS;
      STAGE(s + DIST, sp);
    }

    __builtin_amdgcn_s_setprio(1);
    #pragma unroll
    for (int m = 0; m < 4; m++)
      #pragma unroll
      for (int n = 0; n < 4; n++)
        acc[m][n] = mfma_16x16x32(af[m], bf[n], acc[m][n]);
    __builtin_amdgcn_s_setprio(0);

    if constexpr (MR == 8) {
      bf16x8 af2[4];
      #pragma unroll
      for (int m = 0; m < 4; m++)
        af2[m] = *(const bf16x8*)(As + (wm * 128 + (m + 4) * 16) * 32 + foff);
      __builtin_amdgcn_s_setprio(1);
      #pragma unroll
      for (int m = 0; m < 4; m++)
        #pragma unroll
        for (int n = 0; n < 4; n++)
          acc[m + 4][n] = mfma_16x16x32(af2[m], bf[n], acc[m + 4][n]);
      __builtin_amdgcn_s_setprio(0);
    }

    {
      int im = (s + DIST < NK - 1) ? s + DIST : NK - 1;
      WAITV(im - (s + 1));
    }
    asm volatile("s_waitcnt lgkmcnt(0)" ::: "memory");
    __builtin_amdgcn_sched_barrier(0);
    __builtin_amdgcn_s_barrier();
    __builtin_amdgcn_sched_barrier(0);

    rp = rp + 1 == NS ? 0 : rp + 1;
  }

  #pragma unroll
  for (int n = 0; n < 4; n++) {
    const int gcol = n0 + wn * 64 + n * 16 + fr;
    const float bv = bias ? bias[gcol] : 0.f;
    #pragma unroll
    for (int m = 0; m < MR; m++) {
      #pragma unroll
      for (int r = 0; r < 4; r++) {
        const int grow = m0 + wm * (MR * 16) + m * 16 + g * 4 + r;
        float v = acc[m][n][r] + bv;
        if (ACC) v += bf2f(((const u16*)Cout)[(size_t)grow * ldc + gcol]);
        if (RELU) v = fmaxf(v, 0.f);
        if (OUT_BF16) ((u16*)Cout)[(size_t)grow * ldc + gcol] = f2bf(v);
        else         ((float*)Cout)[(size_t)grow * ldc + gcol] = v;
      }
    }
  }
}

// ---------------------------------------------------------------------------
// Merged K+V projection GEMM (round-11, verified).
// ---------------------------------------------------------------------------
__global__ __launch_bounds__(256, 2) void gemm_kv(
    const u16* __restrict__ A, const u16* __restrict__ Bt,
    const float* __restrict__ biasK, const float* __restrict__ biasV,
    u16* __restrict__ kbf, u16* __restrict__ vtb, int M, int K)
{
  __shared__ u16 ldsA[128 * 32];
  __shared__ u16 ldsB[128 * 32];

  const int tid = threadIdx.x;
  const int lane = tid & 63, wave = tid >> 6;
  const int wr = wave >> 1, wc = wave & 1;
  const int m0 = blockIdx.x * 128, n0 = blockIdx.y * 128;

  const int c0 = tid, c1 = tid + 256;
  const int ar0 = c0 >> 2, ak0 = (c0 & 3) * 8;
  const int ar1 = c1 >> 2, ak1 = (c1 & 3) * 8;

  const bool av0 = (m0 + ar0) < M;
  const bool av1 = (m0 + ar1) < M;
  const u16* Ag0 = A + (size_t)(m0 + ar0) * K + ak0;
  const u16* Ag1 = A + (size_t)(m0 + ar1) * K + ak1;
  const u16* Bg0 = Bt + (size_t)(n0 + ar0) * K + ak0;
  const u16* Bg1 = Bt + (size_t)(n0 + ar1) * K + ak1;

  f32x4 acc[4][4] = {};
  const int fr = lane & 15, fo = (lane >> 4) * 8;

  for (int k0 = 0; k0 < K; k0 += 32) {
    if (av0) gload_lds16(Ag0 + k0, &ldsA[c0 * 8]);
    if (av1) gload_lds16(Ag1 + k0, &ldsA[c1 * 8]);
    gload_lds16(Bg0 + k0, &ldsB[c0 * 8]);
    gload_lds16(Bg1 + k0, &ldsB[c1 * 8]);
    asm volatile("s_waitcnt vmcnt(0)" ::: "memory");
    __syncthreads();

    bf16x8 af[4], bfr[4];
    #pragma unroll
    for (int m = 0; m < 4; m++)
      af[m] = *(const bf16x8*)&ldsA[(wr * 64 + m * 16 + fr) * 32 + fo];
    #pragma unroll
    for (int n = 0; n < 4; n++)
      bfr[n] = *(const bf16x8*)&ldsB[(wc * 64 + n * 16 + fr) * 32 + fo];
    #pragma unroll
    for (int m = 0; m < 4; m++)
      #pragma unroll
      for (int n = 0; n < 4; n++)
        acc[m][n] = mfma_16x16x32(af[m], bfr[n], acc[m][n]);
    __syncthreads();
  }

  const int g = lane >> 4;
  #pragma unroll
  for (int m = 0; m < 4; m++) {
    #pragma unroll
    for (int n = 0; n < 4; n++) {
      const int gcol = n0 + wc * 64 + n * 16 + fr;
      const bool isK = gcol < 1024;
      const int vc = isK ? gcol : gcol - 1024;
      const float bv = isK ? biasK[vc] : biasV[vc];
      #pragma unroll
      for (int r = 0; r < 4; r++) {
        const int grow = m0 + wr * 64 + m * 16 + g * 4 + r;
        if (grow < M) {
          float v = acc[m][n][r] + bv;
          if (isK) {
            kbf[(size_t)grow * 1024 + vc] = f2bf(v);
          } else {
            int bb = grow / 100, jj = grow - bb * 100;
            int h = vc >> 6, d = vc & 63;
            vtb[(size_t)(((bb * 16 + h) * 64 + d)) * 128 + jj] = f2bf(v);
          }
        }
      }
    }
  }
}

// ---------------------------------------------------------------------------
// Weight transpose+convert: src f32 [K][N] -> dst bf16 [N][K]
// ---------------------------------------------------------------------------
__global__ __launch_bounds__(256) void wconv2(const float* __restrict__ src,
                                              u16* __restrict__ dst,
                                              int K, int N)
{
  __shared__ float tile[64][33];
  const int n0 = blockIdx.x * 32, k0 = blockIdx.y * 64;
  const int tx = threadIdx.x & 31, ty = threadIdx.x >> 5;   // 32 x 8
  #pragma unroll
  for (int i = 0; i < 8; i++)
    tile[ty + i * 8][tx] = src[(size_t)(k0 + ty + i * 8) * N + n0 + tx];
  __syncthreads();
  #pragma unroll
  for (int j = 0; j < 4; j++) {
    int n = ty + j * 8;
    uint32_t lo = f2bf(tile[2 * tx][n]);
    uint32_t hi = f2bf(tile[2 * tx + 1][n]);
    *(uint32_t*)&dst[(size_t)(n0 + n) * K + k0 + 2 * tx] = lo | (hi << 16);
  }
}

// Same, but z selects K-weight (z=0) or V-weight (z=1); dst halves contiguous.
__global__ __launch_bounds__(256) void wconv2kv(const float* __restrict__ srcK,
                                                const float* __restrict__ srcV,
                                                u16* __restrict__ dst,
                                                int K, int N)
{
  __shared__ float tile[64][33];
  const int z = blockIdx.z;
  const float* src = z ? srcV : srcK;
  u16* d = dst + (size_t)z * N * K;
  const int n0 = blockIdx.x * 32, k0 = blockIdx.y * 64;
  const int tx = threadIdx.x & 31, ty = threadIdx.x >> 5;
  #pragma unroll
  for (int i = 0; i < 8; i++)
    tile[ty + i * 8][tx] = src[(size_t)(k0 + ty + i * 8) * N + n0 + tx];
  __syncthreads();
  #pragma unroll
  for (int j = 0; j < 4; j++) {
    int n = ty + j * 8;
    uint32_t lo = f2bf(tile[2 * tx][n]);
    uint32_t hi = f2bf(tile[2 * tx + 1][n]);
    *(uint32_t*)&d[(size_t)(n0 + n) * K + k0 + 2 * tx] = lo | (hi << 16);
  }
}

// ---------------------------------------------------------------------------
// Positional encoding add -> bf16 only (fast-math trig)
// ---------------------------------------------------------------------------
__global__ __launch_bounds__(256) void pe_video_k(const float* __restrict__ video,
                                                  u16* __restrict__ vbf)
{
  const int r = blockIdx.x;
  const int s = r & 2047;
  const int d0 = threadIdx.x * 4;
  const size_t base = (size_t)r * 1024 + d0;
  float4 v = *(const float4*)&video[base];
  const float coef = -9.210340371976184f / 1024.f;
  float o[4];
  float in[4] = {v.x, v.y, v.z, v.w};
  #pragma unroll
  for (int i = 0; i < 4; i++) {
    int d = d0 + i;
    int j = d >> 1;
    float dv = __expf((float)(2 * j) * coef);
    float arg = (float)s * dv;
    float pe = (d & 1) ? __cosf(arg) : __sinf(arg);
    o[i] = in[i] + pe;
  }
  uint2 pk;
  pk.x = (uint32_t)f2bf(o[0]) | ((uint32_t)f2bf(o[1]) << 16);
  pk.y = (uint32_t)f2bf(o[2]) | ((uint32_t)f2bf(o[3]) << 16);
  *(uint2*)&vbf[base] = pk;
}

__global__ __launch_bounds__(128) void pe_text_k(const float* __restrict__ text,
                                                 u16* __restrict__ tbf)
{
  const int r = blockIdx.x;
  const int s = r % 100;
  const int d0 = threadIdx.x * 4;
  const size_t base = (size_t)r * 512 + d0;
  float4 v = *(const float4*)&text[base];
  const float coef = -9.210340371976184f / 512.f;
  float o[4];
  float in[4] = {v.x, v.y, v.z, v.w};
  #pragma unroll
  for (int i = 0; i < 4; i++) {
    int d = d0 + i;
    int j = d >> 1;
    float dv = __expf((float)(2 * j) * coef);
    float arg = (float)s * dv;
    float pe = (d & 1) ? __cosf(arg) : __sinf(arg);
    o[i] = in[i] + pe;
  }
  uint2 pk;
  pk.x = (uint32_t)f2bf(o[0]) | ((uint32_t)f2bf(o[1]) << 16);
  pk.y = (uint32_t)f2bf(o[2]) | ((uint32_t)f2bf(o[3]) << 16);
  *(uint2*)&tbf[base] = pk;
}

// ---------------------------------------------------------------------------
// LayerNorm v2: 2 rows/block, 128 threads/row, 16B uint4 loads.
// ---------------------------------------------------------------------------
template<bool LAST>
__global__ __launch_bounds__(256) void ln2v(const u16* __restrict__ xin,
                                            const u16* __restrict__ delta,
                                            const float* __restrict__ gamma,
                                            const float* __restrict__ beta,
                                            u16* __restrict__ xbf,
                                            float* __restrict__ fout)
{
  const int t = threadIdx.x;
  const int rsel = t >> 7;
  const int tr = t & 127;
  const int row = blockIdx.x * 2 + rsel;
  const size_t base = (size_t)row * 1024;
  const int d0 = tr * 8;

  uint4 xv = *(const uint4*)&xin[base + d0];
  uint4 dv = *(const uint4*)&delta[base + d0];
  float v[8];
  {
    const uint32_t xs[4] = {xv.x, xv.y, xv.z, xv.w};
    const uint32_t ds[4] = {dv.x, dv.y, dv.z, dv.w};
    #pragma unroll
    for (int i = 0; i < 4; i++) {
      v[2 * i]     = bf2f((u16)(xs[i] & 0xFFFF)) + bf2f((u16)(ds[i] & 0xFFFF));
      v[2 * i + 1] = bf2f((u16)(xs[i] >> 16))    + bf2f((u16)(ds[i] >> 16));
    }
  }
  float s = 0.f, q = 0.f;
  #pragma unroll
  for (int i = 0; i < 8; i++) { s += v[i]; q += v[i] * v[i]; }
  #pragma unroll
  for (int d = 32; d >= 1; d >>= 1) { s += __shfl_xor(s, d); q += __shfl_xor(q, d); }
  __shared__ float red[8];
  const int w = t >> 6, lane = t & 63;
  if (lane == 0) { red[w] = s; red[4 + w] = q; }
  __syncthreads();
  const float S  = red[rsel * 2] + red[rsel * 2 + 1];
  const float Qs = red[4 + rsel * 2] + red[4 + rsel * 2 + 1];
  const float mu = S * (1.f / 1024.f);
  const float var = Qs * (1.f / 1024.f) - mu * mu;
  const float rs = rsqrtf(var + 1e-5f);

  float4 gv0 = *(const float4*)&gamma[d0];
  float4 gv1 = *(const float4*)&gamma[d0 + 4];
  float4 bv0 = *(const float4*)&beta[d0];
  float4 bv1 = *(const float4*)&beta[d0 + 4];
  const float gs[8] = {gv0.x, gv0.y, gv0.z, gv0.w, gv1.x, gv1.y, gv1.z, gv1.w};
  const float bs[8] = {bv0.x, bv0.y, bv0.z, bv0.w, bv1.x, bv1.y, bv1.z, bv1.w};
  float o[8];
  #pragma unroll
  for (int i = 0; i < 8; i++) o[i] = (v[i] - mu) * rs * gs[i] + bs[i];

  if (LAST) {
    *(float4*)&fout[base + d0]     = make_float4(o[0], o[1], o[2], o[3]);
    *(float4*)&fout[base + d0 + 4] = make_float4(o[4], o[5], o[6], o[7]);
  } else {
    uint4 pk;
    pk.x = (uint32_t)f2bf(o[0]) | ((uint32_t)f2bf(o[1]) << 16);
    pk.y = (uint32_t)f2bf(o[2]) | ((uint32_t)f2bf(o[3]) << 16);
    pk.z = (uint32_t)f2bf(o[4]) | ((uint32_t)f2bf(o[5]) << 16);
    pk.w = (uint32_t)f2bf(o[6]) | ((uint32_t)f2bf(o[7]) << 16);
    *(uint4*)&xbf[base + d0] = pk;
  }
}

// ---------------------------------------------------------------------------
// Cross attention v2 (verified).
// ---------------------------------------------------------------------------
__global__ __launch_bounds__(256) void attn_v2(
    const u16* __restrict__ Q, const u16* __restrict__ Kb,
    const u16* __restrict__ Vtb, const int* __restrict__ mask,
    u16* __restrict__ Out)
{
  __shared__ u16 ldsP[64 * 136];

  const int tid = threadIdx.x, lane = tid & 63, w = tid >> 6;
  const int qb = blockIdx.x, bh = blockIdx.y;
  const int b = bh >> 4, h = bh & 15;
  const int fr = lane & 15, g = lane >> 4, fo = g * 8;

  const size_t qrow = (size_t)(b * 2048 + qb * 64 + w * 16 + fr) * 1024 + h * 64;
  bf16x8 qf0 = *(const bf16x8*)&Q[qrow + fo];
  bf16x8 qf1 = *(const bf16x8*)&Q[qrow + 32 + fo];

  float madd[7];
  #pragma unroll
  for (int t = 0; t < 7; t++) {
    int col = t * 16 + fr;
    int mv = (col < 100) ? mask[b * 100 + col] : 0;
    madd[t] = mv ? 0.f : -1e30f;
  }

  float sc[7][4];
  #pragma unroll
  for (int t = 0; t < 7; t++) {
    int col = t * 16 + fr;
    int jr = (col < 100) ? col : 99;
    const u16* kp = Kb + (size_t)(b * 100 + jr) * 1024 + h * 64;
    bf16x8 kf0 = *(const bf16x8*)&kp[fo];
    bf16x8 kf1 = *(const bf16x8*)&kp[32 + fo];
    f32x4 a = {};
    a = mfma_16x16x32(qf0, kf0, a);
    a = mfma_16x16x32(qf1, kf1, a);
    #pragma unroll
    for (int r = 0; r < 4; r++)
      sc[t][r] = a[r] * 0.125f + madd[t];
  }

  #pragma unroll
  for (int r = 0; r < 4; r++) {
    float m = sc[0][r];
    #pragma unroll
    for (int t = 1; t < 7; t++) m = fmaxf(m, sc[t][r]);
    #pragma unroll
    for (int d = 8; d >= 1; d >>= 1) m = fmaxf(m, __shfl_xor(m, d));
    float ssum = 0.f;
    #pragma unroll
    for (int t = 0; t < 7; t++) { float p = __expf(sc[t][r] - m); sc[t][r] = p; ssum += p; }
    #pragma unroll
    for (int d = 8; d >= 1; d >>= 1) ssum += __shfl_xor(ssum, d);
    float is = 1.f / ssum;
    #pragma unroll
    for (int t = 0; t < 7; t++)
      ldsP[(w * 16 + g * 4 + r) * 136 + t * 16 + fr] = f2bf(sc[t][r] * is);
  }
  {
    u16* zp = &ldsP[(w * 16 + fr) * 136 + 112 + g * 6];
    #pragma unroll
    for (int i = 0; i < 6; i++) zp[i] = 0;
  }

  bf16x8 pa[4];
  #pragma unroll
  for (int kk = 0; kk < 4; kk++)
    pa[kk] = *(const bf16x8*)&ldsP[(w * 16 + fr) * 136 + kk * 32 + fo];
  const u16* vtbase = Vtb + (size_t)bh * 64 * 128;
  #pragma unroll
  for (int nt = 0; nt < 4; nt++) {
    f32x4 a = {};
    #pragma unroll
    for (int kk = 0; kk < 4; kk++) {
      bf16x8 vf = *(const bf16x8*)&vtbase[(size_t)(nt * 16 + fr) * 128 + kk * 32 + fo];
      a = mfma_16x16x32(pa[kk], vf, a);
    }
    #pragma unroll
    for (int r = 0; r < 4; r++) {
      size_t orow = (size_t)(b * 2048 + qb * 64 + w * 16 + g * 4 + r) * 1024 + h * 64 + nt * 16 + fr;
      Out[orow] = f2bf(a[r]);
    }
  }
}

// ---------------------------------------------------------------------------
extern "C" void kernel_launch(void* const* d_in, const int* in_sizes, int n_in,
                              void* d_out, int out_size, void* d_ws, size_t ws_size,
                              hipStream_t stream) {
  const float* video = (const float*)d_in[0];
  const float* text  = (const float*)d_in[1];
  const int*   text_mask = (const int*)d_in[2];
  const float* Wq_w = (const float*)d_in[3];
  const float* Wq_b = (const float*)d_in[4];
  const float* Wk_w = (const float*)d_in[5];
  const float* Wk_b = (const float*)d_in[6];
  const float* Wv_w = (const float*)d_in[7];
  const float* Wv_b = (const float*)d_in[8];
  const float* Wo_w = (const float*)d_in[9];
  const float* Wo_b = (const float*)d_in[10];
  const float* fc1_w = (const float*)d_in[11];
  const float* fc1_b = (const float*)d_in[12];
  const float* fc2_w = (const float*)d_in[13];
  const float* fc2_b = (const float*)d_in[14];
  const float* n2_g = (const float*)d_in[15];
  const float* n2_b = (const float*)d_in[16];
  const float* n3_g = (const float*)d_in[17];
  const float* n3_b = (const float*)d_in[18];

  char* ws = (char*)d_ws;
  size_t off = 0;
  auto alloc = [&](size_t bytes) {
    char* p = ws + off;
    off += (bytes + 255) & ~(size_t)255;
    return p;
  };
  u16* vbf = (u16*)alloc((size_t)8192 * 1024 * 2);     // 16 MB residual (bf16)
  u16* tbf = (u16*)alloc((size_t)400 * 512 * 2);
  u16* wqT = (u16*)alloc((size_t)1024 * 1024 * 2);
  u16* wkT = (u16*)alloc((size_t)1024 * 512 * 2);      // contiguous with wvT
  u16* wvT = (u16*)alloc((size_t)1024 * 512 * 2);
  u16* woT = (u16*)alloc((size_t)1024 * 1024 * 2);
  u16* f1T = (u16*)alloc((size_t)4096 * 1024 * 2);
  u16* f2T = (u16*)alloc((size_t)1024 * 4096 * 2);

  const size_t smallS = 35192832;
  const size_t bigS   = (size_t)8192 * 4096 * 2;
  const size_t tailNeed = 1048576 + 256 + (size_t)8192 * 1024 * 2 + 256;
  const bool big = ws_size >= off + bigS + 256 + tailNeed;

  char* S = alloc(big ? bigS : smallS);
  u16* qbf  = (u16*)S;
  u16* kbf  = (u16*)(S + 16777216);
  u16* abf  = (u16*)(S + 16777216 + 1638400);
  u16* h1   = (u16*)S;
  u16* vtb  = (u16*)alloc((size_t)64 * 64 * 128 * 2);
  u16* dbf  = (u16*)alloc((size_t)8192 * 1024 * 2);
  float* fout = (float*)d_out;

  hipMemsetAsync(vtb, 0, (size_t)64 * 64 * 128 * 2, stream);

  pe_video_k<<<8192, 256, 0, stream>>>(video, vbf);
  pe_text_k<<<400, 128, 0, stream>>>(text, tbf);

  for (int l = 0; l < 4; ++l) {
    wconv2<<<dim3(32, 16), 256, 0, stream>>>(Wq_w + (size_t)l * 1024 * 1024, wqT, 1024, 1024);
    wconv2kv<<<dim3(32, 8, 2), 256, 0, stream>>>(
        Wk_w + (size_t)l * 512 * 1024, Wv_w + (size_t)l * 512 * 1024, wkT, 512, 1024);
    wconv2<<<dim3(32, 16), 256, 0, stream>>>(Wo_w + (size_t)l * 1024 * 1024, woT, 1024, 1024);
    wconv2<<<dim3(128, 16), 256, 0, stream>>>(fc1_w + (size_t)l * 1024 * 4096, f1T, 1024, 4096);
    wconv2<<<dim3(32, 64), 256, 0, stream>>>(fc2_w + (size_t)l * 4096 * 1024, f2T, 4096, 1024);

    gemm_ring<4, true, false, false><<<dim3(64, 4), 512, 0, stream>>>(
        vbf, 1024, wqT, 1024, Wq_b + l * 1024, qbf, 1024, 8192, 1024, 1024);
    gemm_kv<<<dim3(4, 16), 256, 0, stream>>>(
        tbf, wkT, Wk_b + l * 1024, Wv_b + l * 1024, kbf, vtb, 400, 512);
    attn_v2<<<dim3(32, 64), 256, 0, stream>>>(qbf, kbf, vtb, text_mask, abf);
    gemm_ring<4, true, false, false><<<dim3(64, 4), 512, 0, stream>>>(
        abf, 1024, woT, 1024, Wo_b + l * 1024, dbf, 1024, 8192, 1024, 1024);
    ln2v<false><<<4096, 256, 0, stream>>>(vbf, dbf, n2_g + l * 1024, n2_b + l * 1024, vbf, nullptr);

    if (big) {
      gemm_ring<8, true, true, false><<<dim3(32, 16), 512, 0, stream>>>(
          vbf, 1024, f1T, 1024, fc1_b + l * 4096, h1, 4096, 8192, 4096, 1024);
      gemm_ring<4, true, false, false><<<dim3(64, 4), 512, 0, stream>>>(
          h1, 4096, f2T, 4096, fc2_b + l * 1024, dbf, 1024, 8192, 1024, 4096);
    } else {
      for (int c = 0; c < 2; ++c) {
        gemm_ring<8, true, true, false><<<dim3(32, 8), 512, 0, stream>>>(
            vbf, 1024, f1T + (size_t)c * 2048 * 1024, 1024,
            fc1_b + l * 4096 + c * 2048, h1, 2048, 8192, 2048, 1024);
        if (c == 0)
          gemm_ring<4, true, false, false><<<dim3(64, 4), 512, 0, stream>>>(
              h1, 2048, f2T + (size_t)c * 2048, 4096,
              fc2_b + l * 1024, dbf, 1024, 8192, 1024, 2048);
        else
          gemm_ring<4, true, false, true><<<dim3(64, 4), 512, 0, stream>>>(
              h1, 2048, f2T + (size_t)c * 2048, 4096,
              nullptr, dbf, 1024, 8192, 1024, 2048);
      }
    }
    if (l == 3)
      ln2v<true><<<4096, 256, 0, stream>>>(vbf, dbf, n3_g + l * 1024, n3_b + l * 1024, nullptr, fout);
    else
      ln2v<false><<<4096, 256, 0, stream>>>(vbf, dbf, n3_g + l * 1024, n3_b + l * 1024, vbf, nullptr);
  }
}

// Round 18
// 1177.401 us; speedup vs baseline: 1.0119x; 1.0119x over previous
//
#include <hip/hip_runtime.h>
#include <cstdint>
#include <cstddef>

typedef unsigned short u16;
typedef __attribute__((ext_vector_type(8))) __bf16 bf16x8;
typedef __attribute__((ext_vector_type(4))) float f32x4;

__device__ __forceinline__ f32x4 mfma_16x16x32(bf16x8 a, bf16x8 b, f32x4 c) {
  return __builtin_amdgcn_mfma_f32_16x16x32_bf16(a, b, c, 0, 0, 0);
}

__device__ __forceinline__ u16 f2bf(float f) {
  union { float f; uint32_t u; } c; c.f = f;
  uint32_t u = c.u + 0x7FFFu + ((c.u >> 16) & 1u);
  return (u16)(u >> 16);
}

__device__ __forceinline__ float bf2f(u16 x) {
  union { uint32_t u; float f; } c; c.u = ((uint32_t)x) << 16;
  return c.f;
}

__device__ __forceinline__ void gload_lds16(const void* g, void* l) {
  __builtin_amdgcn_global_load_lds(
      (__attribute__((address_space(1))) void*)(uintptr_t)g,
      (__attribute__((address_space(3))) void*)l, 16, 0, 0);
}

// ===========================================================================
// Ring GEMM (final session config = round-5/13/16 best: 4-slot ring, dist 3,
// one barrier/K-step, counted vmcnt, scalar epilogue).  Knob ledger (all
// A/B-tested this session): dist {2-,3*,4-}; barriers/step {1*,2-,4-};
// tile {128^2-, 128x256*, 256x128-, 256^2~}; waves {4-,8*}; epilogue
// {scalar*, LDS-staged-}; swizzle sigma(r)=(r>>1)&3 both sides (conflict 0).
// ===========================================================================
template<int MR, bool OUT_BF16, bool RELU, bool ACC>
__global__ __launch_bounds__(512, 2) void gemm_ring(
    const u16* __restrict__ A, int lda, const u16* __restrict__ Bt, int ldb,
    const float* __restrict__ bias, void* Cout, int ldc,
    int M, int N, int K)
{
  constexpr int BM = MR * 32;
  constexpr int SLOT = (BM + 256) * 32;
  __shared__ u16 ring[4 * SLOT];

  const int tid = threadIdx.x;
  const int lane = tid & 63, wave = tid >> 6;
  const int wm = wave >> 2, wn = wave & 3;
  const int m0 = blockIdx.x * BM, n0 = blockIdx.y * 256;

  const int cA0 = tid, rA0 = cA0 >> 2;
  const u16* gA0 = A + (size_t)(m0 + rA0) * lda + (((cA0 & 3) ^ ((rA0 >> 1) & 3)) * 8);
  const int cA1 = tid + 512, rA1 = cA1 >> 2;
  const u16* gA1 = A + (size_t)(m0 + (MR == 8 ? rA1 : 0)) * lda + (((cA1 & 3) ^ ((rA1 >> 1) & 3)) * 8);
  const int cB0 = tid, rB0 = cB0 >> 2;
  const int cB1 = tid + 512, rB1 = cB1 >> 2;
  const u16* gB0 = Bt + (size_t)(n0 + rB0) * ldb + (((cB0 & 3) ^ ((rB0 >> 1) & 3)) * 8);
  const u16* gB1 = Bt + (size_t)(n0 + rB1) * ldb + (((cB1 & 3) ^ ((rB1 >> 1) & 3)) * 8);

  const int NK = K >> 5;

  auto STAGE = [&](int s) {
    u16* Sb = &ring[(s & 3) * SLOT];
    const int ko = s * 32;
    gload_lds16(gA0 + ko, Sb + cA0 * 8);
    if constexpr (MR == 8) gload_lds16(gA1 + ko, Sb + cA1 * 8);
    gload_lds16(gB0 + ko, Sb + BM * 32 + cB0 * 8);
    gload_lds16(gB1 + ko, Sb + BM * 32 + cB1 * 8);
  };
  auto WAITV = [&](int ahead) {
    if (ahead >= 2) {
      if constexpr (MR == 8) asm volatile("s_waitcnt vmcnt(8)" ::: "memory");
      else                   asm volatile("s_waitcnt vmcnt(6)" ::: "memory");
    } else if (ahead == 1) {
      if constexpr (MR == 8) asm volatile("s_waitcnt vmcnt(4)" ::: "memory");
      else                   asm volatile("s_waitcnt vmcnt(3)" ::: "memory");
    } else {
      asm volatile("s_waitcnt vmcnt(0)" ::: "memory");
    }
  };

  const int fr = lane & 15, g = lane >> 4;
  const int foff = fr * 32 + ((g ^ ((fr >> 1) & 3)) * 8);

  f32x4 acc[MR][4];
  #pragma unroll
  for (int m = 0; m < MR; m++)
    #pragma unroll
    for (int n = 0; n < 4; n++) acc[m][n] = f32x4{0.f, 0.f, 0.f, 0.f};

  for (int i = 0; i < 3 && i < NK; ++i) STAGE(i);
  WAITV(NK - 1 < 2 ? NK - 1 : 2);
  __builtin_amdgcn_s_barrier();
  __builtin_amdgcn_sched_barrier(0);

  for (int s = 0; s < NK; ++s) {
    const u16* As = &ring[(s & 3) * SLOT];
    const u16* Bs = As + BM * 32;

    bf16x8 bf[4];
    #pragma unroll
    for (int n = 0; n < 4; n++)
      bf[n] = *(const bf16x8*)(Bs + (wn * 64 + n * 16) * 32 + foff);
    bf16x8 af[4];
    #pragma unroll
    for (int m = 0; m < 4; m++)
      af[m] = *(const bf16x8*)(As + (wm * (MR * 16) + m * 16) * 32 + foff);

    if (s + 3 < NK) STAGE(s + 3);

    __builtin_amdgcn_s_setprio(1);
    #pragma unroll
    for (int m = 0; m < 4; m++)
      #pragma unroll
      for (int n = 0; n < 4; n++)
        acc[m][n] = mfma_16x16x32(af[m], bf[n], acc[m][n]);
    __builtin_amdgcn_s_setprio(0);

    if constexpr (MR == 8) {
      bf16x8 af2[4];
      #pragma unroll
      for (int m = 0; m < 4; m++)
        af2[m] = *(const bf16x8*)(As + (wm * 128 + (m + 4) * 16) * 32 + foff);
      __builtin_amdgcn_s_setprio(1);
      #pragma unroll
      for (int m = 0; m < 4; m++)
        #pragma unroll
        for (int n = 0; n < 4; n++)
          acc[m + 4][n] = mfma_16x16x32(af2[m], bf[n], acc[m + 4][n]);
      __builtin_amdgcn_s_setprio(0);
    }

    {
      int im = (s + 3 < NK - 1) ? s + 3 : NK - 1;
      WAITV(im - (s + 1));
    }
    asm volatile("s_waitcnt lgkmcnt(0)" ::: "memory");
    __builtin_amdgcn_sched_barrier(0);
    __builtin_amdgcn_s_barrier();
    __builtin_amdgcn_sched_barrier(0);
  }

  #pragma unroll
  for (int n = 0; n < 4; n++) {
    const int gcol = n0 + wn * 64 + n * 16 + fr;
    const float bv = bias ? bias[gcol] : 0.f;
    #pragma unroll
    for (int m = 0; m < MR; m++) {
      #pragma unroll
      for (int r = 0; r < 4; r++) {
        const int grow = m0 + wm * (MR * 16) + m * 16 + g * 4 + r;
        float v = acc[m][n][r] + bv;
        if (ACC) v += bf2f(((const u16*)Cout)[(size_t)grow * ldc + gcol]);
        if (RELU) v = fmaxf(v, 0.f);
        if (OUT_BF16) ((u16*)Cout)[(size_t)grow * ldc + gcol] = f2bf(v);
        else         ((float*)Cout)[(size_t)grow * ldc + gcol] = v;
      }
    }
  }
}

// ---------------------------------------------------------------------------
// Merged K+V projection GEMM (round-11, verified).
// ---------------------------------------------------------------------------
__global__ __launch_bounds__(256, 2) void gemm_kv(
    const u16* __restrict__ A, const u16* __restrict__ Bt,
    const float* __restrict__ biasK, const float* __restrict__ biasV,
    u16* __restrict__ kbf, u16* __restrict__ vtb, int M, int K)
{
  __shared__ u16 ldsA[128 * 32];
  __shared__ u16 ldsB[128 * 32];

  const int tid = threadIdx.x;
  const int lane = tid & 63, wave = tid >> 6;
  const int wr = wave >> 1, wc = wave & 1;
  const int m0 = blockIdx.x * 128, n0 = blockIdx.y * 128;

  const int c0 = tid, c1 = tid + 256;
  const int ar0 = c0 >> 2, ak0 = (c0 & 3) * 8;
  const int ar1 = c1 >> 2, ak1 = (c1 & 3) * 8;

  const bool av0 = (m0 + ar0) < M;
  const bool av1 = (m0 + ar1) < M;
  const u16* Ag0 = A + (size_t)(m0 + ar0) * K + ak0;
  const u16* Ag1 = A + (size_t)(m0 + ar1) * K + ak1;
  const u16* Bg0 = Bt + (size_t)(n0 + ar0) * K + ak0;
  const u16* Bg1 = Bt + (size_t)(n0 + ar1) * K + ak1;

  f32x4 acc[4][4] = {};
  const int fr = lane & 15, fo = (lane >> 4) * 8;

  for (int k0 = 0; k0 < K; k0 += 32) {
    if (av0) gload_lds16(Ag0 + k0, &ldsA[c0 * 8]);
    if (av1) gload_lds16(Ag1 + k0, &ldsA[c1 * 8]);
    gload_lds16(Bg0 + k0, &ldsB[c0 * 8]);
    gload_lds16(Bg1 + k0, &ldsB[c1 * 8]);
    asm volatile("s_waitcnt vmcnt(0)" ::: "memory");
    __syncthreads();

    bf16x8 af[4], bfr[4];
    #pragma unroll
    for (int m = 0; m < 4; m++)
      af[m] = *(const bf16x8*)&ldsA[(wr * 64 + m * 16 + fr) * 32 + fo];
    #pragma unroll
    for (int n = 0; n < 4; n++)
      bfr[n] = *(const bf16x8*)&ldsB[(wc * 64 + n * 16 + fr) * 32 + fo];
    #pragma unroll
    for (int m = 0; m < 4; m++)
      #pragma unroll
      for (int n = 0; n < 4; n++)
        acc[m][n] = mfma_16x16x32(af[m], bfr[n], acc[m][n]);
    __syncthreads();
  }

  const int g = lane >> 4;
  #pragma unroll
  for (int m = 0; m < 4; m++) {
    #pragma unroll
    for (int n = 0; n < 4; n++) {
      const int gcol = n0 + wc * 64 + n * 16 + fr;
      const bool isK = gcol < 1024;
      const int vc = isK ? gcol : gcol - 1024;
      const float bv = isK ? biasK[vc] : biasV[vc];
      #pragma unroll
      for (int r = 0; r < 4; r++) {
        const int grow = m0 + wr * 64 + m * 16 + g * 4 + r;
        if (grow < M) {
          float v = acc[m][n][r] + bv;
          if (isK) {
            kbf[(size_t)grow * 1024 + vc] = f2bf(v);
          } else {
            int bb = grow / 100, jj = grow - bb * 100;
            int h = vc >> 6, d = vc & 63;
            vtb[(size_t)(((bb * 16 + h) * 64 + d)) * 128 + jj] = f2bf(v);
          }
        }
      }
    }
  }
}

// ---------------------------------------------------------------------------
// Weight transpose+convert: src f32 [K][N] -> dst bf16 [N][K]
// ---------------------------------------------------------------------------
__global__ __launch_bounds__(256) void wconv2(const float* __restrict__ src,
                                              u16* __restrict__ dst,
                                              int K, int N)
{
  __shared__ float tile[64][33];
  const int n0 = blockIdx.x * 32, k0 = blockIdx.y * 64;
  const int tx = threadIdx.x & 31, ty = threadIdx.x >> 5;   // 32 x 8
  #pragma unroll
  for (int i = 0; i < 8; i++)
    tile[ty + i * 8][tx] = src[(size_t)(k0 + ty + i * 8) * N + n0 + tx];
  __syncthreads();
  #pragma unroll
  for (int j = 0; j < 4; j++) {
    int n = ty + j * 8;
    uint32_t lo = f2bf(tile[2 * tx][n]);
    uint32_t hi = f2bf(tile[2 * tx + 1][n]);
    *(uint32_t*)&dst[(size_t)(n0 + n) * K + k0 + 2 * tx] = lo | (hi << 16);
  }
}

// Same, but z selects K-weight (z=0) or V-weight (z=1); dst halves contiguous.
__global__ __launch_bounds__(256) void wconv2kv(const float* __restrict__ srcK,
                                                const float* __restrict__ srcV,
                                                u16* __restrict__ dst,
                                                int K, int N)
{
  __shared__ float tile[64][33];
  const int z = blockIdx.z;
  const float* src = z ? srcV : srcK;
  u16* d = dst + (size_t)z * N * K;
  const int n0 = blockIdx.x * 32, k0 = blockIdx.y * 64;
  const int tx = threadIdx.x & 31, ty = threadIdx.x >> 5;
  #pragma unroll
  for (int i = 0; i < 8; i++)
    tile[ty + i * 8][tx] = src[(size_t)(k0 + ty + i * 8) * N + n0 + tx];
  __syncthreads();
  #pragma unroll
  for (int j = 0; j < 4; j++) {
    int n = ty + j * 8;
    uint32_t lo = f2bf(tile[2 * tx][n]);
    uint32_t hi = f2bf(tile[2 * tx + 1][n]);
    *(uint32_t*)&d[(size_t)(n0 + n) * K + k0 + 2 * tx] = lo | (hi << 16);
  }
}

// ---------------------------------------------------------------------------
// Positional encoding add -> bf16 only (fast-math trig)
// ---------------------------------------------------------------------------
__global__ __launch_bounds__(256) void pe_video_k(const float* __restrict__ video,
                                                  u16* __restrict__ vbf)
{
  const int r = blockIdx.x;
  const int s = r & 2047;
  const int d0 = threadIdx.x * 4;
  const size_t base = (size_t)r * 1024 + d0;
  float4 v = *(const float4*)&video[base];
  const float coef = -9.210340371976184f / 1024.f;
  float o[4];
  float in[4] = {v.x, v.y, v.z, v.w};
  #pragma unroll
  for (int i = 0; i < 4; i++) {
    int d = d0 + i;
    int j = d >> 1;
    float dv = __expf((float)(2 * j) * coef);
    float arg = (float)s * dv;
    float pe = (d & 1) ? __cosf(arg) : __sinf(arg);
    o[i] = in[i] + pe;
  }
  uint2 pk;
  pk.x = (uint32_t)f2bf(o[0]) | ((uint32_t)f2bf(o[1]) << 16);
  pk.y = (uint32_t)f2bf(o[2]) | ((uint32_t)f2bf(o[3]) << 16);
  *(uint2*)&vbf[base] = pk;
}

__global__ __launch_bounds__(128) void pe_text_k(const float* __restrict__ text,
                                                 u16* __restrict__ tbf)
{
  const int r = blockIdx.x;
  const int s = r % 100;
  const int d0 = threadIdx.x * 4;
  const size_t base = (size_t)r * 512 + d0;
  float4 v = *(const float4*)&text[base];
  const float coef = -9.210340371976184f / 512.f;
  float o[4];
  float in[4] = {v.x, v.y, v.z, v.w};
  #pragma unroll
  for (int i = 0; i < 4; i++) {
    int d = d0 + i;
    int j = d >> 1;
    float dv = __expf((float)(2 * j) * coef);
    float arg = (float)s * dv;
    float pe = (d & 1) ? __cosf(arg) : __sinf(arg);
    o[i] = in[i] + pe;
  }
  uint2 pk;
  pk.x = (uint32_t)f2bf(o[0]) | ((uint32_t)f2bf(o[1]) << 16);
  pk.y = (uint32_t)f2bf(o[2]) | ((uint32_t)f2bf(o[3]) << 16);
  *(uint2*)&tbf[base] = pk;
}

// ---------------------------------------------------------------------------
// LayerNorm v2: 2 rows/block, 128 threads/row, 16B uint4 loads.
// ---------------------------------------------------------------------------
template<bool LAST>
__global__ __launch_bounds__(256) void ln2v(const u16* __restrict__ xin,
                                            const u16* __restrict__ delta,
                                            const float* __restrict__ gamma,
                                            const float* __restrict__ beta,
                                            u16* __restrict__ xbf,
                                            float* __restrict__ fout)
{
  const int t = threadIdx.x;
  const int rsel = t >> 7;
  const int tr = t & 127;
  const int row = blockIdx.x * 2 + rsel;
  const size_t base = (size_t)row * 1024;
  const int d0 = tr * 8;

  uint4 xv = *(const uint4*)&xin[base + d0];
  uint4 dv = *(const uint4*)&delta[base + d0];
  float v[8];
  {
    const uint32_t xs[4] = {xv.x, xv.y, xv.z, xv.w};
    const uint32_t ds[4] = {dv.x, dv.y, dv.z, dv.w};
    #pragma unroll
    for (int i = 0; i < 4; i++) {
      v[2 * i]     = bf2f((u16)(xs[i] & 0xFFFF)) + bf2f((u16)(ds[i] & 0xFFFF));
      v[2 * i + 1] = bf2f((u16)(xs[i] >> 16))    + bf2f((u16)(ds[i] >> 16));
    }
  }
  float s = 0.f, q = 0.f;
  #pragma unroll
  for (int i = 0; i < 8; i++) { s += v[i]; q += v[i] * v[i]; }
  #pragma unroll
  for (int d = 32; d >= 1; d >>= 1) { s += __shfl_xor(s, d); q += __shfl_xor(q, d); }
  __shared__ float red[8];
  const int w = t >> 6, lane = t & 63;
  if (lane == 0) { red[w] = s; red[4 + w] = q; }
  __syncthreads();
  const float S  = red[rsel * 2] + red[rsel * 2 + 1];
  const float Qs = red[4 + rsel * 2] + red[4 + rsel * 2 + 1];
  const float mu = S * (1.f / 1024.f);
  const float var = Qs * (1.f / 1024.f) - mu * mu;
  const float rs = rsqrtf(var + 1e-5f);

  float4 gv0 = *(const float4*)&gamma[d0];
  float4 gv1 = *(const float4*)&gamma[d0 + 4];
  float4 bv0 = *(const float4*)&beta[d0];
  float4 bv1 = *(const float4*)&beta[d0 + 4];
  const float gs[8] = {gv0.x, gv0.y, gv0.z, gv0.w, gv1.x, gv1.y, gv1.z, gv1.w};
  const float bs[8] = {bv0.x, bv0.y, bv0.z, bv0.w, bv1.x, bv1.y, bv1.z, bv1.w};
  float o[8];
  #pragma unroll
  for (int i = 0; i < 8; i++) o[i] = (v[i] - mu) * rs * gs[i] + bs[i];

  if (LAST) {
    *(float4*)&fout[base + d0]     = make_float4(o[0], o[1], o[2], o[3]);
    *(float4*)&fout[base + d0 + 4] = make_float4(o[4], o[5], o[6], o[7]);
  } else {
    uint4 pk;
    pk.x = (uint32_t)f2bf(o[0]) | ((uint32_t)f2bf(o[1]) << 16);
    pk.y = (uint32_t)f2bf(o[2]) | ((uint32_t)f2bf(o[3]) << 16);
    pk.z = (uint32_t)f2bf(o[4]) | ((uint32_t)f2bf(o[5]) << 16);
    pk.w = (uint32_t)f2bf(o[6]) | ((uint32_t)f2bf(o[7]) << 16);
    *(uint4*)&xbf[base + d0] = pk;
  }
}

// ---------------------------------------------------------------------------
// Cross attention v2 (verified).
// ---------------------------------------------------------------------------
__global__ __launch_bounds__(256) void attn_v2(
    const u16* __restrict__ Q, const u16* __restrict__ Kb,
    const u16* __restrict__ Vtb, const int* __restrict__ mask,
    u16* __restrict__ Out)
{
  __shared__ u16 ldsP[64 * 136];

  const int tid = threadIdx.x, lane = tid & 63, w = tid >> 6;
  const int qb = blockIdx.x, bh = blockIdx.y;
  const int b = bh >> 4, h = bh & 15;
  const int fr = lane & 15, g = lane >> 4, fo = g * 8;

  const size_t qrow = (size_t)(b * 2048 + qb * 64 + w * 16 + fr) * 1024 + h * 64;
  bf16x8 qf0 = *(const bf16x8*)&Q[qrow + fo];
  bf16x8 qf1 = *(const bf16x8*)&Q[qrow + 32 + fo];

  float madd[7];
  #pragma unroll
  for (int t = 0; t < 7; t++) {
    int col = t * 16 + fr;
    int mv = (col < 100) ? mask[b * 100 + col] : 0;
    madd[t] = mv ? 0.f : -1e30f;
  }

  float sc[7][4];
  #pragma unroll
  for (int t = 0; t < 7; t++) {
    int col = t * 16 + fr;
    int jr = (col < 100) ? col : 99;
    const u16* kp = Kb + (size_t)(b * 100 + jr) * 1024 + h * 64;
    bf16x8 kf0 = *(const bf16x8*)&kp[fo];
    bf16x8 kf1 = *(const bf16x8*)&kp[32 + fo];
    f32x4 a = {};
    a = mfma_16x16x32(qf0, kf0, a);
    a = mfma_16x16x32(qf1, kf1, a);
    #pragma unroll
    for (int r = 0; r < 4; r++)
      sc[t][r] = a[r] * 0.125f + madd[t];
  }

  #pragma unroll
  for (int r = 0; r < 4; r++) {
    float m = sc[0][r];
    #pragma unroll
    for (int t = 1; t < 7; t++) m = fmaxf(m, sc[t][r]);
    #pragma unroll
    for (int d = 8; d >= 1; d >>= 1) m = fmaxf(m, __shfl_xor(m, d));
    float ssum = 0.f;
    #pragma unroll
    for (int t = 0; t < 7; t++) { float p = __expf(sc[t][r] - m); sc[t][r] = p; ssum += p; }
    #pragma unroll
    for (int d = 8; d >= 1; d >>= 1) ssum += __shfl_xor(ssum, d);
    float is = 1.f / ssum;
    #pragma unroll
    for (int t = 0; t < 7; t++)
      ldsP[(w * 16 + g * 4 + r) * 136 + t * 16 + fr] = f2bf(sc[t][r] * is);
  }
  {
    u16* zp = &ldsP[(w * 16 + fr) * 136 + 112 + g * 6];
    #pragma unroll
    for (int i = 0; i < 6; i++) zp[i] = 0;
  }

  bf16x8 pa[4];
  #pragma unroll
  for (int kk = 0; kk < 4; kk++)
    pa[kk] = *(const bf16x8*)&ldsP[(w * 16 + fr) * 136 + kk * 32 + fo];
  const u16* vtbase = Vtb + (size_t)bh * 64 * 128;
  #pragma unroll
  for (int nt = 0; nt < 4; nt++) {
    f32x4 a = {};
    #pragma unroll
    for (int kk = 0; kk < 4; kk++) {
      bf16x8 vf = *(const bf16x8*)&vtbase[(size_t)(nt * 16 + fr) * 128 + kk * 32 + fo];
      a = mfma_16x16x32(pa[kk], vf, a);
    }
    #pragma unroll
    for (int r = 0; r < 4; r++) {
      size_t orow = (size_t)(b * 2048 + qb * 64 + w * 16 + g * 4 + r) * 1024 + h * 64 + nt * 16 + fr;
      Out[orow] = f2bf(a[r]);
    }
  }
}

// ---------------------------------------------------------------------------
extern "C" void kernel_launch(void* const* d_in, const int* in_sizes, int n_in,
                              void* d_out, int out_size, void* d_ws, size_t ws_size,
                              hipStream_t stream) {
  const float* video = (const float*)d_in[0];
  const float* text  = (const float*)d_in[1];
  const int*   text_mask = (const int*)d_in[2];
  const float* Wq_w = (const float*)d_in[3];
  const float* Wq_b = (const float*)d_in[4];
  const float* Wk_w = (const float*)d_in[5];
  const float* Wk_b = (const float*)d_in[6];
  const float* Wv_w = (const float*)d_in[7];
  const float* Wv_b = (const float*)d_in[8];
  const float* Wo_w = (const float*)d_in[9];
  const float* Wo_b = (const float*)d_in[10];
  const float* fc1_w = (const float*)d_in[11];
  const float* fc1_b = (const float*)d_in[12];
  const float* fc2_w = (const float*)d_in[13];
  const float* fc2_b = (const float*)d_in[14];
  const float* n2_g = (const float*)d_in[15];
  const float* n2_b = (const float*)d_in[16];
  const float* n3_g = (const float*)d_in[17];
  const float* n3_b = (const float*)d_in[18];

  char* ws = (char*)d_ws;
  size_t off = 0;
  auto alloc = [&](size_t bytes) {
    char* p = ws + off;
    off += (bytes + 255) & ~(size_t)255;
    return p;
  };
  u16* vbf = (u16*)alloc((size_t)8192 * 1024 * 2);     // 16 MB residual (bf16)
  u16* tbf = (u16*)alloc((size_t)400 * 512 * 2);
  u16* wqT = (u16*)alloc((size_t)1024 * 1024 * 2);
  u16* wkT = (u16*)alloc((size_t)1024 * 512 * 2);      // contiguous with wvT
  u16* wvT = (u16*)alloc((size_t)1024 * 512 * 2);
  u16* woT = (u16*)alloc((size_t)1024 * 1024 * 2);
  u16* f1T = (u16*)alloc((size_t)4096 * 1024 * 2);
  u16* f2T = (u16*)alloc((size_t)1024 * 4096 * 2);

  const size_t smallS = 35192832;
  const size_t bigS   = (size_t)8192 * 4096 * 2;
  const size_t tailNeed = 1048576 + 256 + (size_t)8192 * 1024 * 2 + 256;
  const bool big = ws_size >= off + bigS + 256 + tailNeed;

  char* S = alloc(big ? bigS : smallS);
  u16* qbf  = (u16*)S;
  u16* kbf  = (u16*)(S + 16777216);
  u16* abf  = (u16*)(S + 16777216 + 1638400);
  u16* h1   = (u16*)S;
  u16* vtb  = (u16*)alloc((size_t)64 * 64 * 128 * 2);
  u16* dbf  = (u16*)alloc((size_t)8192 * 1024 * 2);
  float* fout = (float*)d_out;

  hipMemsetAsync(vtb, 0, (size_t)64 * 64 * 128 * 2, stream);

  pe_video_k<<<8192, 256, 0, stream>>>(video, vbf);
  pe_text_k<<<400, 128, 0, stream>>>(text, tbf);

  for (int l = 0; l < 4; ++l) {
    wconv2<<<dim3(32, 16), 256, 0, stream>>>(Wq_w + (size_t)l * 1024 * 1024, wqT, 1024, 1024);
    wconv2kv<<<dim3(32, 8, 2), 256, 0, stream>>>(
        Wk_w + (size_t)l * 512 * 1024, Wv_w + (size_t)l * 512 * 1024, wkT, 512, 1024);
    wconv2<<<dim3(32, 16), 256, 0, stream>>>(Wo_w + (size_t)l * 1024 * 1024, woT, 1024, 1024);
    wconv2<<<dim3(128, 16), 256, 0, stream>>>(fc1_w + (size_t)l * 1024 * 4096, f1T, 1024, 4096);
    wconv2<<<dim3(32, 64), 256, 0, stream>>>(fc2_w + (size_t)l * 4096 * 1024, f2T, 4096, 1024);

    gemm_ring<4, true, false, false><<<dim3(64, 4), 512, 0, stream>>>(
        vbf, 1024, wqT, 1024, Wq_b + l * 1024, qbf, 1024, 8192, 1024, 1024);
    gemm_kv<<<dim3(4, 16), 256, 0, stream>>>(
        tbf, wkT, Wk_b + l * 1024, Wv_b + l * 1024, kbf, vtb, 400, 512);
    attn_v2<<<dim3(32, 64), 256, 0, stream>>>(qbf, kbf, vtb, text_mask, abf);
    gemm_ring<4, true, false, false><<<dim3(64, 4), 512, 0, stream>>>(
        abf, 1024, woT, 1024, Wo_b + l * 1024, dbf, 1024, 8192, 1024, 1024);
    ln2v<false><<<4096, 256, 0, stream>>>(vbf, dbf, n2_g + l * 1024, n2_b + l * 1024, vbf, nullptr);

    if (big) {
      gemm_ring<8, true, true, false><<<dim3(32, 16), 512, 0, stream>>>(
          vbf, 1024, f1T, 1024, fc1_b + l * 4096, h1, 4096, 8192, 4096, 1024);
      gemm_ring<4, true, false, false><<<dim3(64, 4), 512, 0, stream>>>(
          h1, 4096, f2T, 4096, fc2_b + l * 1024, dbf, 1024, 8192, 1024, 4096);
    } else {
      for (int c = 0; c < 2; ++c) {
        gemm_ring<8, true, true, false><<<dim3(32, 8), 512, 0, stream>>>(
            vbf, 1024, f1T + (size_t)c * 2048 * 1024, 1024,
            fc1_b + l * 4096 + c * 2048, h1, 2048, 8192, 2048, 1024);
        if (c == 0)
          gemm_ring<4, true, false, false><<<dim3(64, 4), 512, 0, stream>>>(
              h1, 2048, f2T + (size_t)c * 2048, 4096,
              fc2_b + l * 1024, dbf, 1024, 8192, 1024, 2048);
        else
          gemm_ring<4, true, false, true><<<dim3(64, 4), 512, 0, stream>>>(
              h1, 2048, f2T + (size_t)c * 2048, 4096,
              nullptr, dbf, 1024, 8192, 1024, 2048);
      }
    }
    if (l == 3)
      ln2v<true><<<4096, 256, 0, stream>>>(vbf, dbf, n3_g + l * 1024, n3_b + l * 1024, nullptr, fout);
    else
      ln2v<false><<<4096, 256, 0, stream>>>(vbf, dbf, n3_g + l * 1024, n3_b + l * 1024, vbf, nullptr);
  }
}